// Round 4
// baseline (476.561 us; speedup 1.0000x reference)
//
#include <hip/hip_runtime.h>
#include <stdint.h>

// Problem constants
#define BATCH   16384
#define MEM_DIM 4096
#define FEAT    1024
#define LAMBD   0.00048828125f   // 2.0 / 4096
#define SEPS    1e-12f

typedef __attribute__((ext_vector_type(8))) short short8;
typedef __attribute__((ext_vector_type(4))) float f32x4;

__device__ __forceinline__ unsigned short f2bf(float x) {
  uint32_t u = __builtin_bit_cast(uint32_t, x);
  u += 0x7fffu + ((u >> 16) & 1u);   // round-to-nearest-even
  return (unsigned short)(u >> 16);
}
__device__ __forceinline__ float bf2f(unsigned short b) {
  uint32_t u = ((uint32_t)b) << 16;
  return __builtin_bit_cast(float, u);
}

// ---------------- fused prep: z cast | mem cast + transpose ----------------
// blocks [0,8192): z f32 -> zb bf16 (2048 elems each)
// blocks [8192,12288): 32x32 mem tile -> memb (row-major) + membT (transposed)
__global__ __launch_bounds__(256) void prep_kernel(
    const float* __restrict__ z, const float* __restrict__ mem,
    unsigned short* __restrict__ zb, unsigned short* __restrict__ memb,
    unsigned short* __restrict__ membT) {
  const int b = blockIdx.x;
  if (b < 8192) {
    size_t i = ((size_t)b * 256 + threadIdx.x) * 8;
    f32x4 a = __builtin_nontemporal_load((const f32x4*)(z + i));
    f32x4 c = __builtin_nontemporal_load((const f32x4*)(z + i + 4));
    union { unsigned short u[8]; short8 v; } r;
    r.u[0] = f2bf(a.x); r.u[1] = f2bf(a.y); r.u[2] = f2bf(a.z); r.u[3] = f2bf(a.w);
    r.u[4] = f2bf(c.x); r.u[5] = f2bf(c.y); r.u[6] = f2bf(c.z); r.u[7] = f2bf(c.w);
    *(short8*)(zb + i) = r.v;
  } else {
    __shared__ unsigned short tile[32][33];
    const int bb = b - 8192;
    const int mt = bb & 127;            // MEM_DIM/32 = 128
    const int ct = bb >> 7;             // FEAT/32 = 32
    const int tx = threadIdx.x & 31;
    const int ty = threadIdx.x >> 5;
    #pragma unroll
    for (int r = ty; r < 32; r += 8) {
      const unsigned short bf =
          f2bf(__builtin_nontemporal_load(mem + (size_t)(mt * 32 + r) * FEAT + ct * 32 + tx));
      tile[r][tx] = bf;
      memb[(size_t)(mt * 32 + r) * FEAT + ct * 32 + tx] = bf;
    }
    __syncthreads();
    #pragma unroll
    for (int r = ty; r < 32; r += 8)
      membT[(size_t)(ct * 32 + r) * MEM_DIM + mt * 32 + tx] = tile[tx][r];
  }
}

// =====================================================================
// 256x256 8-phase bt-GEMM, persistent-chained over CHAIN bm-segments.
// C[M,N] = A[M,K] * Bt[N,K]^T  (bf16 in, f32 acc)
// 512 threads = 8 waves (2M x 4N), BK=64, 2 K-tiles/iter, 8 phases/iter.
// LDS 128KB: [dbuf][A|B][half 128x64] st_16x32-swizzled subtiled layout.
// =====================================================================

#define LDSB(db, ab, h) ((((db)*2 + (ab))*2 + (h)) * 16384)

#define CFENCE asm volatile("" ::: "memory")
#define BAR()  do { CFENCE; __builtin_amdgcn_s_barrier(); CFENCE; } while (0)
#define LGKM0  asm volatile("s_waitcnt lgkmcnt(0)" ::: "memory")
#define VM4    asm volatile("s_waitcnt vmcnt(4)" ::: "memory")

// stage one 128x64 half-tile (16KB) = 2 x global_load_lds(16B) per thread.
// LDS dest is linear; global source is inverse-swizzled (rel0/rel1).
#define STAGE(src, base, h, db, ab, kb) do {                                        \
    __builtin_amdgcn_global_load_lds(                                               \
      (const __attribute__((address_space(1))) uint32_t*)((src) + (base) +          \
          (size_t)(h) * 128 * KC + rel0 + (kb)),                                    \
      (__attribute__((address_space(3))) uint32_t*)(lds + LDSB(db, ab, h) + tid*16),\
      16, 0, 0);                                                                    \
    __builtin_amdgcn_global_load_lds(                                               \
      (const __attribute__((address_space(1))) uint32_t*)((src) + (base) +          \
          (size_t)(h) * 128 * KC + rel1 + (kb)),                                    \
      (__attribute__((address_space(3))) uint32_t*)(lds + LDSB(db, ab, h) + 8192 +  \
          tid*16),                                                                  \
      16, 0, 0);                                                                    \
  } while (0)

#define RD_A(db, mh)                                                                \
  _Pragma("unroll") for (int mi = 0; mi < 4; ++mi) {                                \
    _Pragma("unroll") for (int kk = 0; kk < 2; ++kk)                                \
      af[mi][kk] = *(const short8*)(aP##db + ((mh) << 13) + (mi << 11) + (kk << 10)); \
  }

#define RD_B2(db, n0)                                                               \
  _Pragma("unroll") for (int ni = 0; ni < 2; ++ni) {                                \
    _Pragma("unroll") for (int kk = 0; kk < 2; ++kk)                                \
      bfr[(n0) + ni][kk] = *(const short8*)(bP##db + (((n0) + ni) << 11) + (kk << 10)); \
  }

#define MFMA_Q(mh, nh) do {                                                         \
    __builtin_amdgcn_s_setprio(1);                                                  \
    _Pragma("unroll") for (int mi = 0; mi < 4; ++mi)                                \
    _Pragma("unroll") for (int ni = 0; ni < 2; ++ni)                                \
    _Pragma("unroll") for (int kk = 0; kk < 2; ++kk)                                \
      acc[(mh)*4 + mi][(nh)*2 + ni] = __builtin_amdgcn_mfma_f32_16x16x32_bf16(      \
          af[mi][kk], bfr[(nh)*2 + ni][kk], acc[(mh)*4 + mi][(nh)*2 + ni], 0, 0, 0);\
    __builtin_amdgcn_s_setprio(0);                                                  \
  } while (0)

template<bool OUT_BF16, int KC, int CHAIN, int NBN>
__global__ __launch_bounds__(512, 2)
void gemm256(const unsigned short* __restrict__ A, const unsigned short* __restrict__ Bt,
             float* __restrict__ Cf, unsigned short* __restrict__ Cb, const int ldc)
{
  constexpr int NT = KC / 64;            // K-tiles per segment
  constexpr int LOG2NT = (NT == 16) ? 4 : 6;
  constexpr int HNIT = NT / 2;           // iters per segment

  __shared__ __align__(16) char lds[131072];

  const int tid  = threadIdx.x;
  const int lane = tid & 63;
  const int wid  = tid >> 6;
  const int wm = wid >> 2;
  const int wn = wid & 3;
  const int lrow = lane & 15;
  const int lkg  = lane >> 4;

  // block -> (bm0, bn) mapping, XCD-aware
  int bm0, bn;
  if constexpr (CHAIN == 4) {
    // 256 blocks: 16 groups x 16 bn; the 16 blocks of a group share A panels
    // and land on one XCD (orig%8 == grp%8) for L2 A-reuse.
    const int bid = (int)blockIdx.x;
    const int xcd = bid & 7;
    const int t   = bid >> 3;            // 0..31
    const int ghi = t >> 4;              // 0..1
    bn = t & 15;
    const int grp = ghi * 8 + xcd;       // 0..15
    bm0 = grp * 4;
  } else {
    const int nwg = (int)gridDim.x;
    int wg = (int)blockIdx.x;
    wg = (wg & 7) * (nwg >> 3) + (wg >> 3);
    bm0 = wg / NBN;
    bn  = wg % NBN;
  }

  // ---- staging source offsets: invert st_16x32 swizzle for linear LDS dest ----
  size_t rel0, rel1;
  {
    #pragma unroll
    for (int j = 0; j < 2; ++j) {
      const int c = j * 512 + tid;
      const int d = c * 16;
      const int s = d >> 10;
      int w = d & 1023;
      w ^= ((w >> 9) & 1) << 5;
      const int row  = ((s >> 1) << 4) + (w >> 6);
      const int colE = ((s & 1) << 5) + ((w & 63) >> 1);
      const size_t r = (size_t)row * KC + colE;
      if (j == 0) rel0 = r; else rel1 = r;
    }
  }
  const size_t baseA0 = (size_t)bm0 * 256 * KC;
  const size_t segStep = (size_t)256 * KC;
  const size_t baseB = (size_t)bn * 256 * KC;

  auto baseAOf = [&](int g) {
    int s = g >> LOG2NT;
    if (s >= CHAIN) s = CHAIN - 1;
    return baseA0 + (size_t)s * segStep;
  };
  auto kbOf = [&](int g) { return (g & (NT - 1)) * 64; };

  // per-lane swizzled LDS read base (bytes within a half)
  const int lane_base = (((lrow << 6) | (lkg << 4)) ^ ((((lrow >> 3) & 1)) << 5));
  const char* aP0 = lds + LDSB(0, 0, 0) + wm * 16384 + lane_base;
  const char* aP1 = lds + LDSB(1, 0, 0) + wm * 16384 + lane_base;
  const char* bP0 = lds + LDSB(0, 1, 0) + (wn >> 1) * 16384 + ((wn & 1) << 13) + lane_base;
  const char* bP1 = lds + LDSB(1, 1, 0) + (wn >> 1) * 16384 + ((wn & 1) << 13) + lane_base;

  f32x4 acc[8][4] = {};
  short8 af[4][2], bfr[4][2];

  // ---- prologue: dbuf0 <- ktile0 (A+B), dbuf1 <- ktile1 (B; A staged in P1/P2) ----
  STAGE(A,  baseA0, 0, 0, 0, 0);
  STAGE(A,  baseA0, 1, 0, 0, 0);
  STAGE(Bt, baseB, 0, 0, 1, 0);
  STAGE(Bt, baseB, 1, 0, 1, 0);
  STAGE(Bt, baseB, 0, 1, 1, 64);
  STAGE(Bt, baseB, 1, 1, 1, 64);
  VM4;
  BAR();

  #pragma unroll 1
  for (int git = 0; git < CHAIN * HNIT; ++git) {
    const int g1 = 2 * git + 1, g2 = 2 * git + 2, g3 = 2 * git + 3;
    const size_t bA1 = baseAOf(g1), bA2 = baseAOf(g2);
    const int kb1 = kbOf(g1), kb2 = kbOf(g2), kb3 = kbOf(g3);

    // ---- phases 1-4: compute dbuf0 (K-tile 2git) ----
    RD_A(0, 0); RD_B2(0, 0);
    STAGE(A, bA1, 0, 1, 0, kb1);              // dbuf1 A-h0 (ktile g1)
    BAR(); LGKM0; MFMA_Q(0, 0); BAR();
    RD_B2(0, 2);
    STAGE(A, bA1, 1, 1, 0, kb1);              // dbuf1 A-h1
    BAR(); LGKM0; MFMA_Q(0, 1); BAR();
    RD_A(0, 1);
    STAGE(Bt, baseB, 0, 0, 1, kb2);           // dbuf0 B-h0 (ktile g2)
    BAR(); LGKM0; MFMA_Q(1, 0); BAR();
    STAGE(Bt, baseB, 1, 0, 1, kb2);           // dbuf0 B-h1
    BAR(); LGKM0; MFMA_Q(1, 1); VM4; BAR();   // dbuf1 complete

    // ---- phases 5-8: compute dbuf1 (K-tile 2git+1) ----
    RD_A(1, 0); RD_B2(1, 0);
    STAGE(A, bA2, 0, 0, 0, kb2);              // dbuf0 A-h0 (ktile g2; may be next segment)
    BAR(); LGKM0; MFMA_Q(0, 0); BAR();
    RD_B2(1, 2);
    STAGE(A, bA2, 1, 0, 0, kb2);              // dbuf0 A-h1
    BAR(); LGKM0; MFMA_Q(0, 1); BAR();
    RD_A(1, 1);
    STAGE(Bt, baseB, 0, 1, 1, kb3);           // dbuf1 B-h0 (ktile g3)
    BAR(); LGKM0; MFMA_Q(1, 0); BAR();
    STAGE(Bt, baseB, 1, 1, 1, kb3);           // dbuf1 B-h1
    BAR(); LGKM0; MFMA_Q(1, 1); VM4; BAR();   // dbuf0 complete

    // ---- segment epilogue: write this segment's C tile, reset acc ----
    if (((git + 1) & (HNIT - 1)) == 0) {
      const int s = ((git + 1) >> (LOG2NT - 1)) - 1;
      const int row0 = (bm0 + s) * 256 + wm * 128 + lkg * 4;
      const int col0 = bn * 256 + wn * 64 + lrow;
      #pragma unroll
      for (int mi = 0; mi < 8; ++mi)
        #pragma unroll
        for (int ni = 0; ni < 4; ++ni) {
          #pragma unroll
          for (int r = 0; r < 4; ++r) {
            const size_t row = row0 + mi * 16 + r;
            const int col = col0 + ni * 16;
            if (OUT_BF16) Cb[row * ldc + col] = f2bf(acc[mi][ni][r]);
            else __builtin_nontemporal_store(acc[mi][ni][r], &Cf[row * ldc + col]);
          }
          acc[mi][ni] = (f32x4){0.f, 0.f, 0.f, 0.f};
        }
    }
  }
}

// ---------------- fused softmax -> hard_shrink_relu -> softmax ----------------
__device__ __forceinline__ float block_reduce_max(float v, float* sred) {
  #pragma unroll
  for (int o = 32; o > 0; o >>= 1) v = fmaxf(v, __shfl_xor(v, o, 64));
  __syncthreads();
  if ((threadIdx.x & 63) == 0) sred[threadIdx.x >> 6] = v;
  __syncthreads();
  return fmaxf(fmaxf(sred[0], sred[1]), fmaxf(sred[2], sred[3]));
}
__device__ __forceinline__ float block_reduce_sum(float v, float* sred) {
  #pragma unroll
  for (int o = 32; o > 0; o >>= 1) v += __shfl_xor(v, o, 64);
  __syncthreads();
  if ((threadIdx.x & 63) == 0) sred[threadIdx.x >> 6] = v;
  __syncthreads();
  return (sred[0] + sred[1]) + (sred[2] + sred[3]);
}

__global__ __launch_bounds__(256)
void softmax_shrink_kernel(const unsigned short* __restrict__ W,
                           float* __restrict__ att,
                           unsigned short* __restrict__ attb)
{
  __shared__ float sred[4];
  const int row = blockIdx.x;
  const int tid = threadIdx.x;
  const unsigned short* wrp = W + (size_t)row * MEM_DIM + tid * 16;

  union { short8 v; unsigned short u[8]; } l0, l1;
  l0.v = *(const short8*)wrp;
  l1.v = *(const short8*)(wrp + 8);
  float v[16];
  #pragma unroll
  for (int j = 0; j < 8; ++j) { v[j] = bf2f(l0.u[j]); v[8 + j] = bf2f(l1.u[j]); }

  float m = v[0];
  #pragma unroll
  for (int j = 1; j < 16; ++j) m = fmaxf(m, v[j]);
  m = block_reduce_max(m, sred);
  float s = 0.f, e[16];
  #pragma unroll
  for (int j = 0; j < 16; ++j) { e[j] = __expf(v[j] - m); s += e[j]; }
  const float inv1 = 1.f / block_reduce_sum(s, sred);

  float wh[16];
  #pragma unroll
  for (int j = 0; j < 16; ++j) {
    const float p = e[j] * inv1;
    const float d = p - LAMBD;
    wh[j] = (d > 0.f) ? (d * p / (d + SEPS)) : 0.f;
  }

  float m2 = wh[0];
  #pragma unroll
  for (int j = 1; j < 16; ++j) m2 = fmaxf(m2, wh[j]);
  m2 = block_reduce_max(m2, sred);
  float s2 = 0.f, a[16];
  #pragma unroll
  for (int j = 0; j < 16; ++j) { a[j] = __expf(wh[j] - m2); s2 += a[j]; }
  const float inv2 = 1.f / block_reduce_sum(s2, sred);

  float* arow = att + (size_t)row * MEM_DIM + tid * 16;
  #pragma unroll
  for (int j = 0; j < 16; j += 4) {
    f32x4 o = {a[j] * inv2, a[j+1] * inv2, a[j+2] * inv2, a[j+3] * inv2};
    __builtin_nontemporal_store(o, (f32x4*)(arow + j));   // att f32 never re-read
  }
  union { short8 v; unsigned short u[8]; } s0, s1;
  #pragma unroll
  for (int j = 0; j < 8; ++j) { s0.u[j] = f2bf(a[j] * inv2); s1.u[j] = f2bf(a[8 + j] * inv2); }
  unsigned short* ab = attb + (size_t)row * MEM_DIM + tid * 16;
  *(short8*)ab = s0.v;          // re-read by GEMM2 -> keep cacheable
  *(short8*)(ab + 8) = s1.v;
}

// ---------------- launcher ----------------
extern "C" void kernel_launch(void* const* d_in, const int* in_sizes, int n_in,
                              void* d_out, int out_size, void* d_ws, size_t ws_size,
                              hipStream_t stream) {
  const float* z   = (const float*)d_in[0];   // [16384, 1024]
  const float* mem = (const float*)d_in[1];   // [4096, 1024]
  float* att_out  = (float*)d_out;
  float* zhat_out = (float*)d_out + (size_t)BATCH * MEM_DIM;

  unsigned short* zb    = (unsigned short*)d_ws;
  unsigned short* memb  = zb + (size_t)BATCH * FEAT;
  unsigned short* membT = memb + (size_t)MEM_DIM * FEAT;
  unsigned short* wbuf  = membT + (size_t)FEAT * MEM_DIM;

  prep_kernel<<<8192 + 4096, 256, 0, stream>>>(z, mem, zb, memb, membT);

  // GEMM1: w = z @ mem^T  [16384,4096], K=1024, bf16 out; 256 persistent blocks x 4 bm-segments
  gemm256<true, FEAT, 4, 16><<<256, 512, 0, stream>>>(zb, memb, nullptr, wbuf, MEM_DIM);

  softmax_shrink_kernel<<<BATCH, 256, 0, stream>>>(wbuf, att_out, wbuf);

  // GEMM2: z_hat = att @ (memT)^T  [16384,1024], K=4096, f32 out
  gemm256<false, MEM_DIM, 1, 4><<<256, 512, 0, stream>>>(wbuf, membT, zhat_out, nullptr, FEAT);
}

// Round 5
// 358.447 us; speedup vs baseline: 1.3295x; 1.3295x over previous
//
#include <hip/hip_runtime.h>
#include <stdint.h>

// Problem constants
#define BATCH   16384
#define MEM_DIM 4096
#define FEAT    1024
#define LAMBD   0.00048828125f   // 2.0 / 4096
#define SEPS    1e-12f

typedef __attribute__((ext_vector_type(8))) short short8;
typedef __attribute__((ext_vector_type(4))) float f32x4;

__device__ __forceinline__ unsigned short f2bf(float x) {
  uint32_t u = __builtin_bit_cast(uint32_t, x);
  u += 0x7fffu + ((u >> 16) & 1u);   // round-to-nearest-even
  return (unsigned short)(u >> 16);
}
__device__ __forceinline__ float bf2f(unsigned short b) {
  uint32_t u = ((uint32_t)b) << 16;
  return __builtin_bit_cast(float, u);
}

// ---------------- fused prep: z cast | mem cast + transpose ----------------
__global__ __launch_bounds__(256) void prep_kernel(
    const float* __restrict__ z, const float* __restrict__ mem,
    unsigned short* __restrict__ zb, unsigned short* __restrict__ memb,
    unsigned short* __restrict__ membT) {
  const int b = blockIdx.x;
  if (b < 8192) {
    size_t i = ((size_t)b * 256 + threadIdx.x) * 8;
    f32x4 a = __builtin_nontemporal_load((const f32x4*)(z + i));
    f32x4 c = __builtin_nontemporal_load((const f32x4*)(z + i + 4));
    union { unsigned short u[8]; short8 v; } r;
    r.u[0] = f2bf(a.x); r.u[1] = f2bf(a.y); r.u[2] = f2bf(a.z); r.u[3] = f2bf(a.w);
    r.u[4] = f2bf(c.x); r.u[5] = f2bf(c.y); r.u[6] = f2bf(c.z); r.u[7] = f2bf(c.w);
    *(short8*)(zb + i) = r.v;
  } else {
    __shared__ unsigned short tile[32][33];
    const int bb = b - 8192;
    const int mt = bb & 127;            // MEM_DIM/32 = 128
    const int ct = bb >> 7;             // FEAT/32 = 32
    const int tx = threadIdx.x & 31;
    const int ty = threadIdx.x >> 5;
    #pragma unroll
    for (int r = ty; r < 32; r += 8) {
      const unsigned short bf =
          f2bf(__builtin_nontemporal_load(mem + (size_t)(mt * 32 + r) * FEAT + ct * 32 + tx));
      tile[r][tx] = bf;
      memb[(size_t)(mt * 32 + r) * FEAT + ct * 32 + tx] = bf;
    }
    __syncthreads();
    #pragma unroll
    for (int r = ty; r < 32; r += 8)
      membT[(size_t)(ct * 32 + r) * MEM_DIM + mt * 32 + tx] = tile[tx][r];
  }
}

// =====================================================================
// 256x256 8-phase bt-GEMM, persistent-chained over CHAIN bm-segments.
// =====================================================================

#define LDSB(db, ab, h) ((((db)*2 + (ab))*2 + (h)) * 16384)

#define CFENCE asm volatile("" ::: "memory")
#define BAR()  do { CFENCE; __builtin_amdgcn_s_barrier(); CFENCE; } while (0)
#define LGKM0  asm volatile("s_waitcnt lgkmcnt(0)" ::: "memory")
#define VM4    asm volatile("s_waitcnt vmcnt(4)" ::: "memory")

#define STAGE(src, base, h, db, ab, kb) do {                                        \
    __builtin_amdgcn_global_load_lds(                                               \
      (const __attribute__((address_space(1))) uint32_t*)((src) + (base) +          \
          (size_t)(h) * 128 * KC + rel0 + (kb)),                                    \
      (__attribute__((address_space(3))) uint32_t*)(lds + LDSB(db, ab, h) + tid*16),\
      16, 0, 0);                                                                    \
    __builtin_amdgcn_global_load_lds(                                               \
      (const __attribute__((address_space(1))) uint32_t*)((src) + (base) +          \
          (size_t)(h) * 128 * KC + rel1 + (kb)),                                    \
      (__attribute__((address_space(3))) uint32_t*)(lds + LDSB(db, ab, h) + 8192 +  \
          tid*16),                                                                  \
      16, 0, 0);                                                                    \
  } while (0)

#define RD_A(db, mh)                                                                \
  _Pragma("unroll") for (int mi = 0; mi < 4; ++mi) {                                \
    _Pragma("unroll") for (int kk = 0; kk < 2; ++kk)                                \
      af[mi][kk] = *(const short8*)(aP##db + ((mh) << 13) + (mi << 11) + (kk << 10)); \
  }

#define RD_B2(db, n0)                                                               \
  _Pragma("unroll") for (int ni = 0; ni < 2; ++ni) {                                \
    _Pragma("unroll") for (int kk = 0; kk < 2; ++kk)                                \
      bfr[(n0) + ni][kk] = *(const short8*)(bP##db + (((n0) + ni) << 11) + (kk << 10)); \
  }

#define MFMA_Q(mh, nh) do {                                                         \
    __builtin_amdgcn_s_setprio(1);                                                  \
    _Pragma("unroll") for (int mi = 0; mi < 4; ++mi)                                \
    _Pragma("unroll") for (int ni = 0; ni < 2; ++ni)                                \
    _Pragma("unroll") for (int kk = 0; kk < 2; ++kk)                                \
      acc[(mh)*4 + mi][(nh)*2 + ni] = __builtin_amdgcn_mfma_f32_16x16x32_bf16(      \
          af[mi][kk], bfr[(nh)*2 + ni][kk], acc[(mh)*4 + mi][(nh)*2 + ni], 0, 0, 0);\
    __builtin_amdgcn_s_setprio(0);                                                  \
  } while (0)

template<bool OUT_BF16, int KC, int CHAIN, int NBN>
__global__ __launch_bounds__(512, 2)
void gemm256(const unsigned short* __restrict__ A, const unsigned short* __restrict__ Bt,
             float* __restrict__ Cf, unsigned short* __restrict__ Cb, const int ldc)
{
  constexpr int NT = KC / 64;            // K-tiles per segment
  constexpr int LOG2NT = (NT == 16) ? 4 : 6;
  constexpr int HNIT = NT / 2;           // iters per segment

  __shared__ __align__(16) char lds[131072];

  const int tid  = threadIdx.x;
  const int lane = tid & 63;
  const int wid  = tid >> 6;
  const int wm = wid >> 2;
  const int wn = wid & 3;
  const int lrow = lane & 15;
  const int lkg  = lane >> 4;

  // block -> (bm0, bn) mapping, XCD-aware
  int bm0, bn;
  if constexpr (CHAIN == 4) {
    const int bid = (int)blockIdx.x;
    const int xcd = bid & 7;
    const int t   = bid >> 3;
    const int ghi = t >> 4;
    bn = t & 15;
    const int grp = ghi * 8 + xcd;
    bm0 = grp * 4;
  } else {
    const int nwg = (int)gridDim.x;
    int wg = (int)blockIdx.x;
    wg = (wg & 7) * (nwg >> 3) + (wg >> 3);
    bm0 = wg / NBN;
    bn  = wg % NBN;
  }

  // staging source offsets: invert st_16x32 swizzle for linear LDS dest
  size_t rel0, rel1;
  {
    #pragma unroll
    for (int j = 0; j < 2; ++j) {
      const int c = j * 512 + tid;
      const int d = c * 16;
      const int s = d >> 10;
      int w = d & 1023;
      w ^= ((w >> 9) & 1) << 5;
      const int row  = ((s >> 1) << 4) + (w >> 6);
      const int colE = ((s & 1) << 5) + ((w & 63) >> 1);
      const size_t r = (size_t)row * KC + colE;
      if (j == 0) rel0 = r; else rel1 = r;
    }
  }
  const size_t baseA0 = (size_t)bm0 * 256 * KC;
  const size_t segStep = (size_t)256 * KC;
  const size_t baseB = (size_t)bn * 256 * KC;

  auto baseAOf = [&](int g) {
    int s = g >> LOG2NT;
    if (s >= CHAIN) s = CHAIN - 1;
    return baseA0 + (size_t)s * segStep;
  };
  auto kbOf = [&](int g) { return (g & (NT - 1)) * 64; };

  const int lane_base = (((lrow << 6) | (lkg << 4)) ^ ((((lrow >> 3) & 1)) << 5));
  const char* aP0 = lds + LDSB(0, 0, 0) + wm * 16384 + lane_base;
  const char* aP1 = lds + LDSB(1, 0, 0) + wm * 16384 + lane_base;
  const char* bP0 = lds + LDSB(0, 1, 0) + (wn >> 1) * 16384 + ((wn & 1) << 13) + lane_base;
  const char* bP1 = lds + LDSB(1, 1, 0) + (wn >> 1) * 16384 + ((wn & 1) << 13) + lane_base;

  f32x4 acc[8][4] = {};
  short8 af[4][2], bfr[4][2];

  // prologue
  STAGE(A,  baseA0, 0, 0, 0, 0);
  STAGE(A,  baseA0, 1, 0, 0, 0);
  STAGE(Bt, baseB, 0, 0, 1, 0);
  STAGE(Bt, baseB, 1, 0, 1, 0);
  STAGE(Bt, baseB, 0, 1, 1, 64);
  STAGE(Bt, baseB, 1, 1, 1, 64);
  VM4;
  BAR();

  #pragma unroll 1
  for (int git = 0; git < CHAIN * HNIT; ++git) {
    const int g1 = 2 * git + 1, g2 = 2 * git + 2, g3 = 2 * git + 3;
    const size_t bA1 = baseAOf(g1), bA2 = baseAOf(g2);
    const int kb1 = kbOf(g1), kb2 = kbOf(g2), kb3 = kbOf(g3);

    // phases 1-4: compute dbuf0 (K-tile 2git)
    RD_A(0, 0); RD_B2(0, 0);
    STAGE(A, bA1, 0, 1, 0, kb1);
    BAR(); LGKM0; MFMA_Q(0, 0); BAR();
    RD_B2(0, 2);
    STAGE(A, bA1, 1, 1, 0, kb1);
    BAR(); LGKM0; MFMA_Q(0, 1); BAR();
    RD_A(0, 1);
    STAGE(Bt, baseB, 0, 0, 1, kb2);
    BAR(); LGKM0; MFMA_Q(1, 0); BAR();
    STAGE(Bt, baseB, 1, 0, 1, kb2);
    BAR(); LGKM0; MFMA_Q(1, 1); VM4; BAR();

    // phases 5-8: compute dbuf1 (K-tile 2git+1)
    RD_A(1, 0); RD_B2(1, 0);
    STAGE(A, bA2, 0, 0, 0, kb2);
    BAR(); LGKM0; MFMA_Q(0, 0); BAR();
    RD_B2(1, 2);
    STAGE(A, bA2, 1, 0, 0, kb2);
    BAR(); LGKM0; MFMA_Q(0, 1); BAR();
    RD_A(1, 1);
    STAGE(Bt, baseB, 0, 1, 1, kb3);
    BAR(); LGKM0; MFMA_Q(1, 0); BAR();
    STAGE(Bt, baseB, 1, 1, 1, kb3);
    BAR(); LGKM0; MFMA_Q(1, 1); VM4; BAR();

    // segment epilogue
    if (((git + 1) & (HNIT - 1)) == 0) {
      const int s = ((git + 1) >> (LOG2NT - 1)) - 1;
      const int row0 = (bm0 + s) * 256 + wm * 128 + lkg * 4;
      const int col0 = bn * 256 + wn * 64 + lrow;
      #pragma unroll
      for (int mi = 0; mi < 8; ++mi)
        #pragma unroll
        for (int ni = 0; ni < 4; ++ni) {
          #pragma unroll
          for (int r = 0; r < 4; ++r) {
            const size_t row = row0 + mi * 16 + r;
            const int col = col0 + ni * 16;
            if (OUT_BF16) Cb[row * ldc + col] = f2bf(acc[mi][ni][r]);
            else          Cf[row * ldc + col] = acc[mi][ni][r];
          }
          acc[mi][ni] = (f32x4){0.f, 0.f, 0.f, 0.f};
        }
    }
  }
}

// ---------------- wave-per-row softmax -> hard_shrink_relu -> softmax ----------------
// One 64-lane wave owns a full 4096-elem row in registers (64 f32/lane).
// All reductions are 6-step shfl_xor; no LDS, no barriers. 4 rows/block.
__global__ __launch_bounds__(256, 4)
void softmax_shrink_kernel(const unsigned short* __restrict__ W,
                           float* __restrict__ att,
                           unsigned short* __restrict__ attb)
{
  const int lane = threadIdx.x & 63;
  const int row  = blockIdx.x * 4 + (threadIdx.x >> 6);
  const unsigned short* wr = W + (size_t)row * MEM_DIM;

  float v[64];
  #pragma unroll
  for (int c = 0; c < 8; ++c) {
    union { short8 s; unsigned short u[8]; } x;
    x.s = *(const short8*)(wr + c * 512 + lane * 8);
    #pragma unroll
    for (int j = 0; j < 8; ++j) v[c * 8 + j] = bf2f(x.u[j]);
  }

  // ---- softmax 1 ----
  float m0 = v[0], m1 = v[1], m2 = v[2], m3 = v[3];
  #pragma unroll
  for (int j = 4; j < 64; j += 4) {
    m0 = fmaxf(m0, v[j]); m1 = fmaxf(m1, v[j + 1]);
    m2 = fmaxf(m2, v[j + 2]); m3 = fmaxf(m3, v[j + 3]);
  }
  float m = fmaxf(fmaxf(m0, m1), fmaxf(m2, m3));
  #pragma unroll
  for (int o = 32; o > 0; o >>= 1) m = fmaxf(m, __shfl_xor(m, o, 64));

  float s0 = 0.f, s1 = 0.f, s2 = 0.f, s3 = 0.f;
  #pragma unroll
  for (int j = 0; j < 64; j += 4) {
    v[j]     = __expf(v[j]     - m); s0 += v[j];
    v[j + 1] = __expf(v[j + 1] - m); s1 += v[j + 1];
    v[j + 2] = __expf(v[j + 2] - m); s2 += v[j + 2];
    v[j + 3] = __expf(v[j + 3] - m); s3 += v[j + 3];
  }
  float s = (s0 + s1) + (s2 + s3);
  #pragma unroll
  for (int o = 32; o > 0; o >>= 1) s += __shfl_xor(s, o, 64);
  const float inv1 = 1.f / s;

  // ---- hard_shrink_relu (in place) ----
  #pragma unroll
  for (int j = 0; j < 64; ++j) {
    const float p = v[j] * inv1;
    const float d = p - LAMBD;
    v[j] = (d > 0.f) ? (d * p / (d + SEPS)) : 0.f;
  }

  // ---- softmax 2 ----
  m0 = v[0]; m1 = v[1]; m2 = v[2]; m3 = v[3];
  #pragma unroll
  for (int j = 4; j < 64; j += 4) {
    m0 = fmaxf(m0, v[j]); m1 = fmaxf(m1, v[j + 1]);
    m2 = fmaxf(m2, v[j + 2]); m3 = fmaxf(m3, v[j + 3]);
  }
  float mm = fmaxf(fmaxf(m0, m1), fmaxf(m2, m3));
  #pragma unroll
  for (int o = 32; o > 0; o >>= 1) mm = fmaxf(mm, __shfl_xor(mm, o, 64));

  s0 = s1 = s2 = s3 = 0.f;
  #pragma unroll
  for (int j = 0; j < 64; j += 4) {
    v[j]     = __expf(v[j]     - mm); s0 += v[j];
    v[j + 1] = __expf(v[j + 1] - mm); s1 += v[j + 1];
    v[j + 2] = __expf(v[j + 2] - mm); s2 += v[j + 2];
    v[j + 3] = __expf(v[j + 3] - mm); s3 += v[j + 3];
  }
  s = (s0 + s1) + (s2 + s3);
  #pragma unroll
  for (int o = 32; o > 0; o >>= 1) s += __shfl_xor(s, o, 64);
  const float inv2 = 1.f / s;

  float* arow = att + (size_t)row * MEM_DIM;
  unsigned short* ab = attb + (size_t)row * MEM_DIM;
  #pragma unroll
  for (int c = 0; c < 8; ++c) {
    const int base = c * 512 + lane * 8;
    f32x4 o0 = {v[c*8] * inv2, v[c*8+1] * inv2, v[c*8+2] * inv2, v[c*8+3] * inv2};
    f32x4 o1 = {v[c*8+4] * inv2, v[c*8+5] * inv2, v[c*8+6] * inv2, v[c*8+7] * inv2};
    *(f32x4*)(arow + base)     = o0;
    *(f32x4*)(arow + base + 4) = o1;
    union { short8 s; unsigned short u[8]; } r;
    r.u[0] = f2bf(o0.x); r.u[1] = f2bf(o0.y); r.u[2] = f2bf(o0.z); r.u[3] = f2bf(o0.w);
    r.u[4] = f2bf(o1.x); r.u[5] = f2bf(o1.y); r.u[6] = f2bf(o1.z); r.u[7] = f2bf(o1.w);
    *(short8*)(ab + base) = r.s;
  }
}

// ---------------- launcher ----------------
extern "C" void kernel_launch(void* const* d_in, const int* in_sizes, int n_in,
                              void* d_out, int out_size, void* d_ws, size_t ws_size,
                              hipStream_t stream) {
  const float* z   = (const float*)d_in[0];   // [16384, 1024]
  const float* mem = (const float*)d_in[1];   // [4096, 1024]
  float* att_out  = (float*)d_out;
  float* zhat_out = (float*)d_out + (size_t)BATCH * MEM_DIM;

  unsigned short* zb    = (unsigned short*)d_ws;
  unsigned short* memb  = zb + (size_t)BATCH * FEAT;
  unsigned short* membT = memb + (size_t)MEM_DIM * FEAT;
  unsigned short* wbuf  = membT + (size_t)FEAT * MEM_DIM;

  prep_kernel<<<8192 + 4096, 256, 0, stream>>>(z, mem, zb, memb, membT);

  // GEMM1: w = z @ mem^T  [16384,4096], K=1024, bf16 out; 256 persistent blocks x 4 bm-segments
  gemm256<true, FEAT, 4, 16><<<256, 512, 0, stream>>>(zb, memb, nullptr, wbuf, MEM_DIM);

  // fused double-softmax + hardshrink; wave-per-row
  softmax_shrink_kernel<<<BATCH / 4, 256, 0, stream>>>(wbuf, att_out, wbuf);

  // GEMM2: z_hat = att @ (memT)^T  [16384,1024], K=4096, f32 out
  gemm256<false, MEM_DIM, 1, 4><<<256, 512, 0, stream>>>(wbuf, membT, zhat_out, nullptr, FEAT);
}